// Round 2
// baseline (695.465 us; speedup 1.0000x reference)
//
#include <hip/hip_runtime.h>
#include <hip/hip_bf16.h>
#include <hip/hip_fp16.h>

// ============================================================================
// MinGRUCell forward, MI355X (gfx950).  Round 2: inputs/outputs are FP32
// (reference file says jnp.float32; round-1 bf16 interpretation gave NaN —
// classic wrong-dtype bit-pattern poisoning).
//
//   zh = x @ W^T + b          (N,L,2H) -- x,W rounded to bf16, MFMA GEMM
//   a[t] = sigmoid(-z[t]); v[t] = sigmoid(z[t]) * g(h_inter[t])
//   h[t] = a[t]*h[t-1] + v[t], h[-1] = hx   (linear-space scan == reference's
//   log-space Heinsen scan; all terms positive, max|h| ~ 4.9)
//
// Workspace (~140 MB, same footprint class as round 1 which ran):
//   wb    bf16 (2048,1024)    4 MB   -- W pre-converted
//   zbuf  fp16 (M,H)         67 MB   -- store z (not sigmoid) for rel precision
//   hbuf  fp16 (M,H)         67 MB
//   Aar/Bar/seed fp32 16*8192 each (1.5 MB)
// x is converted fp32->bf16 in GEMM staging registers (no x_bf16 buffer).
// ============================================================================

#define N_B   8
#define L_SEQ 4096
#define H_DIM 1024
#define K_DIM 1024
#define O_DIM 2048
#define M_TOT (N_B * L_SEQ)      // 32768 GEMM rows

#define BM 128
#define BN 128
#define BK 64

#define NCHUNK 16
#define CLEN   (L_SEQ / NCHUNK)  // 256
#define NCH    (N_B * H_DIM)     // 8192 channels

typedef unsigned short ushort_t;
typedef unsigned short us8 __attribute__((ext_vector_type(8)));
typedef __bf16 v8bf __attribute__((ext_vector_type(8)));
typedef float f32x4 __attribute__((ext_vector_type(4)));

static __device__ __forceinline__ ushort_t f2bf(float f) {
    __hip_bfloat16 h = __float2bfloat16(f);   // RTN
    return *reinterpret_cast<ushort_t*>(&h);
}

// ---------------------------------------------------------------------------
// W fp32 -> bf16 (2M elements, 8 per thread)
// ---------------------------------------------------------------------------
__global__ __launch_bounds__(256) void cvt_w(
    const float* __restrict__ src, ushort_t* __restrict__ dst)
{
    const int i = blockIdx.x * 256 + threadIdx.x;    // 0..262143
    const float4 f0 = ((const float4*)src)[2 * i];
    const float4 f1 = ((const float4*)src)[2 * i + 1];
    us8 o;
    o[0] = f2bf(f0.x); o[1] = f2bf(f0.y); o[2] = f2bf(f0.z); o[3] = f2bf(f0.w);
    o[4] = f2bf(f1.x); o[5] = f2bf(f1.y); o[6] = f2bf(f1.z); o[7] = f2bf(f1.w);
    ((us8*)dst)[i] = o;
}

// ---------------------------------------------------------------------------
// GEMM: C[m,o] = sum_k x[m,k]*W[o,k] + b[o]   (NT, both row-major)
// 128x128 C-tile, 4 waves (2x2 of 64x64), mfma_f32_16x16x32_bf16.
// LDS XOR-swizzled by row (chunk c of row m at c ^ (m&7)): ds_read_b128
// fragment reads are <=2-way bank-aliased (free, m136).
// A staged from fp32 x with in-register bf16 conversion; B from bf16 wb.
// ---------------------------------------------------------------------------
__global__ __launch_bounds__(256) void gemm_zh(
    const float* __restrict__ X,           // (M_TOT, K) fp32
    const ushort_t* __restrict__ Wb,       // (O_DIM, K) bf16 bits
    const float* __restrict__ bias,        // (O_DIM) fp32
    __half* __restrict__ zbuf,             // (M_TOT, H_DIM) fp16
    __half* __restrict__ hbuf)             // (M_TOT, H_DIM) fp16
{
    __shared__ ushort_t As[BM * BK];
    __shared__ ushort_t Bs[BN * BK];

    const int tid    = threadIdx.x;
    const int wave   = tid >> 6;
    const int lane   = tid & 63;
    const int lane15 = lane & 15;
    const int quad   = lane >> 4;

    const int n0 = blockIdx.x * BN;        // O-tile fast -> A-tile L2 reuse
    const int m0 = blockIdx.y * BM;

    // staging: thread covers rows (r*32 + tid>>3), dest 16B-chunk tid&7
    const int srow = tid >> 3;             // 0..31
    const int sj   = tid & 7;
    const int jj   = sj ^ (srow & 7);      // xor swizzle; (row&7) == (srow&7)
    const float*    gA = X  + (size_t)(m0 + srow) * K_DIM + jj * 8;
    const ushort_t* gB = Wb + (size_t)(n0 + srow) * K_DIM + jj * 8;

    const int wm = (wave >> 1) * 64;
    const int wn = (wave & 1) * 64;

    // LDS fragment offsets (elements). A-frag: A[m=lane15][k=quad*8+j].
    int offA[2][4], offB[2][4];
#pragma unroll
    for (int s = 0; s < 2; ++s) {
#pragma unroll
        for (int t = 0; t < 4; ++t) {
            const int rowA = wm + t * 16 + lane15;
            offA[s][t] = rowA * BK + (((s * 4 + quad) ^ (rowA & 7)) * 8);
            const int rowB = wn + t * 16 + lane15;
            offB[s][t] = rowB * BK + (((s * 4 + quad) ^ (rowB & 7)) * 8);
        }
    }

    const f32x4 fzero = {0.f, 0.f, 0.f, 0.f};
    f32x4 acc[4][4];
#pragma unroll
    for (int i = 0; i < 4; ++i)
#pragma unroll
        for (int j = 0; j < 4; ++j)
            acc[i][j] = fzero;

    for (int kt = 0; kt < K_DIM / BK; ++kt) {
        us8 ta[4], tb[4];
#pragma unroll
        for (int r = 0; r < 4; ++r) {
            const float4* pA = (const float4*)(gA + (size_t)r * 32 * K_DIM + kt * BK);
            const float4 f0 = pA[0];
            const float4 f1 = pA[1];
            us8 t;
            t[0] = f2bf(f0.x); t[1] = f2bf(f0.y); t[2] = f2bf(f0.z); t[3] = f2bf(f0.w);
            t[4] = f2bf(f1.x); t[5] = f2bf(f1.y); t[6] = f2bf(f1.z); t[7] = f2bf(f1.w);
            ta[r] = t;
            tb[r] = *(const us8*)(gB + (size_t)r * 32 * K_DIM + kt * BK);
        }
        __syncthreads();   // previous iteration done reading LDS
#pragma unroll
        for (int r = 0; r < 4; ++r) {
            *(us8*)(&As[(r * 32 + srow) * BK + sj * 8]) = ta[r];
            *(us8*)(&Bs[(r * 32 + srow) * BK + sj * 8]) = tb[r];
        }
        __syncthreads();

#pragma unroll
        for (int s = 0; s < 2; ++s) {
            v8bf af[4], bfr[4];
#pragma unroll
            for (int t = 0; t < 4; ++t) af[t]  = *(const v8bf*)(&As[offA[s][t]]);
#pragma unroll
            for (int t = 0; t < 4; ++t) bfr[t] = *(const v8bf*)(&Bs[offB[s][t]]);
#pragma unroll
            for (int i = 0; i < 4; ++i)
#pragma unroll
                for (int j = 0; j < 4; ++j)
                    acc[i][j] = __builtin_amdgcn_mfma_f32_16x16x32_bf16(
                        af[i], bfr[j], acc[i][j], 0, 0, 0);
        }
    }

    // Epilogue. C/D layout (m89-verified): col = lane&15, row = quad*4 + reg.
    float bv[4];
#pragma unroll
    for (int j = 0; j < 4; ++j)
        bv[j] = bias[n0 + wn + j * 16 + lane15];

    __half* outb = (n0 < H_DIM) ? zbuf : hbuf;      // block-uniform
    const int colbase = (n0 & (H_DIM - 1)) + wn + lane15;

#pragma unroll
    for (int i = 0; i < 4; ++i) {
#pragma unroll
        for (int r = 0; r < 4; ++r) {
            const size_t row = (size_t)(m0 + wm + i * 16 + quad * 4 + r);
            __half* p = outb + row * H_DIM + colbase;
#pragma unroll
            for (int j = 0; j < 4; ++j)
                p[j * 16] = __float2half(acc[i][j][r] + bv[j]);
        }
    }
}

// ---------------------------------------------------------------------------
// Gating math (identical in phases 1 and 3).
// a = sigmoid(-z), v = sigmoid(z)*g(hi);  g(x) = x+0.5 (x>=0) else sigmoid(x)
// ---------------------------------------------------------------------------
__device__ __forceinline__ void gate_av(float z, float hi, float& a, float& v)
{
    const float e  = __expf(-z);
    const float sz = 1.0f / (1.0f + e);        // sigmoid(z)
    a = e * sz;                                // sigmoid(-z)
    const float g = (hi >= 0.0f) ? (hi + 0.5f)
                                 : (1.0f / (1.0f + __expf(-hi)));
    v = sz * g;
}

// Phase 1: per-(channel-pair, chunk) affine summary  h_out = A*h_in + B.
__global__ __launch_bounds__(256) void scan_phase1(
    const __half* __restrict__ zbuf, const __half* __restrict__ hbuf,
    float* __restrict__ Aar, float* __restrict__ Bar)
{
    const int idx = blockIdx.x * 256 + threadIdx.x;   // 0..65535
    const int h2  = (idx & 511) << 1;
    const int n   = (idx >> 9) & 7;
    const int c   = idx >> 12;
    const size_t base = ((size_t)(n * L_SEQ + c * CLEN)) * H_DIM + h2;
    const __half2* zp = (const __half2*)(zbuf + base);
    const __half2* hp = (const __half2*)(hbuf + base);

    float A0 = 1.f, B0 = 0.f, A1 = 1.f, B1 = 0.f;
#pragma unroll 8
    for (int s = 0; s < CLEN; ++s) {
        const float2 z  = __half22float2(zp[(size_t)s * (H_DIM / 2)]);
        const float2 hi = __half22float2(hp[(size_t)s * (H_DIM / 2)]);
        float a, v;
        gate_av(z.x, hi.x, a, v);  B0 = fmaf(a, B0, v);  A0 *= a;
        gate_av(z.y, hi.y, a, v);  B1 = fmaf(a, B1, v);  A1 *= a;
    }
    *(float2*)(Aar + 2 * (size_t)idx) = make_float2(A0, A1);
    *(float2*)(Bar + 2 * (size_t)idx) = make_float2(B0, B1);
}

// Phase 2: compose 16 chunk summaries per channel, seeded with hx (fp32).
__global__ __launch_bounds__(256) void scan_phase2(
    const float* __restrict__ Aar, const float* __restrict__ Bar,
    const float* __restrict__ hx, float* __restrict__ seed)
{
    const int ch = blockIdx.x * 256 + threadIdx.x;    // 0..8191
    float carry = hx[ch];
#pragma unroll
    for (int c = 0; c < NCHUNK; ++c) {
        seed[c * NCH + ch] = carry;
        carry = fmaf(Aar[c * NCH + ch], carry, Bar[c * NCH + ch]);
    }
}

// Phase 3: replay each chunk from its seed, write fp32 output.
__global__ __launch_bounds__(256) void scan_phase3(
    const __half* __restrict__ zbuf, const __half* __restrict__ hbuf,
    const float* __restrict__ seed, float* __restrict__ out)
{
    const int idx = blockIdx.x * 256 + threadIdx.x;
    const int h2  = (idx & 511) << 1;
    const int n   = (idx >> 9) & 7;
    const int c   = idx >> 12;
    const size_t base = ((size_t)(n * L_SEQ + c * CLEN)) * H_DIM + h2;
    const __half2* zp = (const __half2*)(zbuf + base);
    const __half2* hp = (const __half2*)(hbuf + base);
    float* op = out + base;

    float2 hcur = *(const float2*)(seed + 2 * (size_t)idx);
#pragma unroll 4
    for (int s = 0; s < CLEN; ++s) {
        const float2 z  = __half22float2(zp[(size_t)s * (H_DIM / 2)]);
        const float2 hi = __half22float2(hp[(size_t)s * (H_DIM / 2)]);
        float a, v;
        gate_av(z.x, hi.x, a, v);  hcur.x = fmaf(a, hcur.x, v);
        gate_av(z.y, hi.y, a, v);  hcur.y = fmaf(a, hcur.y, v);
        *(float2*)(op + (size_t)s * H_DIM) = hcur;
    }
}

// ---------------------------------------------------------------------------
extern "C" void kernel_launch(void* const* d_in, const int* in_sizes, int n_in,
                              void* d_out, int out_size, void* d_ws, size_t ws_size,
                              hipStream_t stream)
{
    const float* X    = (const float*)d_in[0];   // x  (8,4096,1024) fp32
    const float* Wm   = (const float*)d_in[1];   // W  (2048,1024)   fp32
    const float* bias = (const float*)d_in[2];   // b  (2048)        fp32
    const float* hx   = (const float*)d_in[3];   // hx (8,1024)      fp32
    float* out = (float*)d_out;                  // (8,4096,1024)    fp32

    char* ws = (char*)d_ws;
    ushort_t* wb = (ushort_t*)ws;                                  //  4 MB
    __half* zbuf = (__half*)(ws + (size_t)O_DIM * K_DIM * 2);      // 67 MB
    __half* hbuf = zbuf + (size_t)M_TOT * H_DIM;                   // 67 MB
    float*  Aar  = (float*)(hbuf + (size_t)M_TOT * H_DIM);
    float*  Bar  = Aar + (size_t)NCHUNK * NCH;
    float*  seed = Bar + (size_t)NCHUNK * NCH;

    cvt_w<<<O_DIM * K_DIM / 8 / 256, 256, 0, stream>>>(Wm, wb);

    dim3 ggrid(O_DIM / BN, M_TOT / BM);          // (16, 256): O fast for reuse
    gemm_zh<<<ggrid, 256, 0, stream>>>(X, wb, bias, zbuf, hbuf);

    const int p13_blocks = (NCH / 2) * NCHUNK / 256;   // 256
    scan_phase1<<<p13_blocks, 256, 0, stream>>>(zbuf, hbuf, Aar, Bar);
    scan_phase2<<<NCH / 256, 256, 0, stream>>>(Aar, Bar, hx, seed);
    scan_phase3<<<p13_blocks, 256, 0, stream>>>(zbuf, hbuf, seed, out);
}

// Round 3
// 499.461 us; speedup vs baseline: 1.3924x; 1.3924x over previous
//
#include <hip/hip_runtime.h>
#include <hip/hip_bf16.h>
#include <hip/hip_fp16.h>

// ============================================================================
// MinGRUCell forward, MI355X (gfx950).  Round 3.
//   zh = x @ W^T + b     (x,W rounded to bf16, MFMA GEMM, global_load_lds)
//   h[t] = sigmoid(-z)*h[t-1] + sigmoid(z)*g(h_inter), h[-1]=hx  (linear scan)
//
// Round-2 passed (absmax 0.031, 695 us). This round:
//  - GEMM staging via global_load_lds width=16 (m93->m97 = 1.7x step).
//    Requires bf16 A in global: x is pre-converted fp32->bf16 into the FIRST
//    HALF OF d_out (scratch until phase3 overwrites it; stream-ordered).
//  - Scan chunks 16->64: 4096 waves (16/CU) instead of 1024 (1/SIMD) -- the
//    round-2 scan was latency-bound at 1 wave/SIMD (~440 us of the 695).
//
// Workspace (~145 MB): wb bf16 4MB | zbuf fp16 67MB | hbuf fp16 67MB |
//                      Aar/Bar/seed fp32 2MB each
// ============================================================================

#define N_B   8
#define L_SEQ 4096
#define H_DIM 1024
#define K_DIM 1024
#define O_DIM 2048
#define M_TOT (N_B * L_SEQ)      // 32768 GEMM rows

#define BM 128
#define BN 128
#define BK 64

#define NCHUNK 64
#define CLEN   (L_SEQ / NCHUNK)  // 64
#define NCH    (N_B * H_DIM)     // 8192 channels

typedef unsigned short ushort_t;
typedef unsigned short us8 __attribute__((ext_vector_type(8)));
typedef __bf16 v8bf __attribute__((ext_vector_type(8)));
typedef float f32x4 __attribute__((ext_vector_type(4)));

static __device__ __forceinline__ ushort_t f2bf(float f) {
    __hip_bfloat16 h = __float2bfloat16(f);   // RTN
    return *reinterpret_cast<ushort_t*>(&h);
}

// async global->LDS DMA, 16B per lane, LDS dest = wave-uniform base + lane*16
static __device__ __forceinline__ void dma16(const ushort_t* g, ushort_t* l) {
    __builtin_amdgcn_global_load_lds(
        (const __attribute__((address_space(1))) unsigned int*)g,
        (__attribute__((address_space(3))) unsigned int*)l,
        16, 0, 0);
}

// ---------------------------------------------------------------------------
// fp32 -> bf16 converters (8 elems/thread, float4 in, us8 out)
// ---------------------------------------------------------------------------
__global__ __launch_bounds__(256) void cvt_f32_bf16(
    const float* __restrict__ src, ushort_t* __restrict__ dst)
{
    const int i = blockIdx.x * 256 + threadIdx.x;
    const float4 f0 = ((const float4*)src)[2 * i];
    const float4 f1 = ((const float4*)src)[2 * i + 1];
    us8 o;
    o[0] = f2bf(f0.x); o[1] = f2bf(f0.y); o[2] = f2bf(f0.z); o[3] = f2bf(f0.w);
    o[4] = f2bf(f1.x); o[5] = f2bf(f1.y); o[6] = f2bf(f1.z); o[7] = f2bf(f1.w);
    ((us8*)dst)[i] = o;
}

// ---------------------------------------------------------------------------
// GEMM: C[m,o] = sum_k xb[m,k]*Wb[o,k] + b[o]   (NT, both row-major, bf16)
// 128x128 C-tile, 4 waves (2x2 of 64x64), mfma_f32_16x16x32_bf16.
// Staging: global_load_lds dwordx4. Lane l of a wave DMAs 16B; HW writes
// LDS base + l*16, which in our row-major [row][BK] tile covers 8 rows x 8
// chunk-slots with slot = l&7, row offset = l>>3. The XOR swizzle (chunk c of
// row r lives at slot c^(r&7)) therefore rides on the GLOBAL source address:
// lane l reads global chunk (l&7)^(l>>3) of its row. Fragment ds_read_b128s
// then see <=2-way bank aliasing (free, m136).
// ---------------------------------------------------------------------------
__global__ __launch_bounds__(256) void gemm_zh(
    const ushort_t* __restrict__ Xb,       // (M_TOT, K) bf16 bits
    const ushort_t* __restrict__ Wb,       // (O_DIM, K) bf16 bits
    const float* __restrict__ bias,        // (O_DIM) fp32
    __half* __restrict__ zbuf,             // (M_TOT, H_DIM) fp16
    __half* __restrict__ hbuf)             // (M_TOT, H_DIM) fp16
{
    __shared__ ushort_t As[BM * BK];
    __shared__ ushort_t Bs[BN * BK];

    const int tid    = threadIdx.x;
    const int wave   = tid >> 6;
    const int lane   = tid & 63;
    const int lane15 = lane & 15;
    const int quad   = lane >> 4;

    const int n0 = blockIdx.x * BN;        // O-tile fast -> A-tile L2 reuse
    const int m0 = blockIdx.y * BM;

    // DMA staging: wave covers rows (r*32 + wave*8 + (lane>>3)), r=0..3,
    // global chunk jj = (lane&7) ^ (lane>>3)   [== slot ^ (row&7)]
    const int lrow = lane >> 3;            // 0..7
    const int jj   = (lane & 7) ^ lrow;
    const ushort_t* gA = Xb + (size_t)(m0 + wave * 8 + lrow) * K_DIM + jj * 8;
    const ushort_t* gB = Wb + (size_t)(n0 + wave * 8 + lrow) * K_DIM + jj * 8;
    ushort_t* lA = &As[(wave * 8) * BK];   // wave-uniform LDS bases
    ushort_t* lB = &Bs[(wave * 8) * BK];

    const int wm = (wave >> 1) * 64;
    const int wn = (wave & 1) * 64;

    // LDS fragment offsets (elements). A-frag: A[m=lane15][k=quad*8+j].
    int offA[2][4], offB[2][4];
#pragma unroll
    for (int s = 0; s < 2; ++s) {
#pragma unroll
        for (int t = 0; t < 4; ++t) {
            const int rowA = wm + t * 16 + lane15;
            offA[s][t] = rowA * BK + (((s * 4 + quad) ^ (rowA & 7)) * 8);
            const int rowB = wn + t * 16 + lane15;
            offB[s][t] = rowB * BK + (((s * 4 + quad) ^ (rowB & 7)) * 8);
        }
    }

    const f32x4 fzero = {0.f, 0.f, 0.f, 0.f};
    f32x4 acc[4][4];
#pragma unroll
    for (int i = 0; i < 4; ++i)
#pragma unroll
        for (int j = 0; j < 4; ++j)
            acc[i][j] = fzero;

    for (int kt = 0; kt < K_DIM / BK; ++kt) {
        __syncthreads();                   // prev iter done reading LDS
#pragma unroll
        for (int r = 0; r < 4; ++r) {
            dma16(gA + (size_t)r * 32 * K_DIM + kt * BK, lA + r * 32 * BK);
            dma16(gB + (size_t)r * 32 * K_DIM + kt * BK, lB + r * 32 * BK);
        }
        __syncthreads();                   // drains vmcnt -> LDS visible

#pragma unroll
        for (int s = 0; s < 2; ++s) {
            v8bf af[4], bfr[4];
#pragma unroll
            for (int t = 0; t < 4; ++t) af[t]  = *(const v8bf*)(&As[offA[s][t]]);
#pragma unroll
            for (int t = 0; t < 4; ++t) bfr[t] = *(const v8bf*)(&Bs[offB[s][t]]);
#pragma unroll
            for (int i = 0; i < 4; ++i)
#pragma unroll
                for (int j = 0; j < 4; ++j)
                    acc[i][j] = __builtin_amdgcn_mfma_f32_16x16x32_bf16(
                        af[i], bfr[j], acc[i][j], 0, 0, 0);
        }
    }

    // Epilogue. C/D layout (m89-verified): col = lane&15, row = quad*4 + reg.
    float bv[4];
#pragma unroll
    for (int j = 0; j < 4; ++j)
        bv[j] = bias[n0 + wn + j * 16 + lane15];

    __half* outb = (n0 < H_DIM) ? zbuf : hbuf;      // block-uniform
    const int colbase = (n0 & (H_DIM - 1)) + wn + lane15;

#pragma unroll
    for (int i = 0; i < 4; ++i) {
#pragma unroll
        for (int r = 0; r < 4; ++r) {
            const size_t row = (size_t)(m0 + wm + i * 16 + quad * 4 + r);
            __half* p = outb + row * H_DIM + colbase;
#pragma unroll
            for (int j = 0; j < 4; ++j)
                p[j * 16] = __float2half(acc[i][j][r] + bv[j]);
        }
    }
}

// ---------------------------------------------------------------------------
// Gating math (identical in phases 1 and 3).
// a = sigmoid(-z), v = sigmoid(z)*g(hi);  g(x) = x+0.5 (x>=0) else sigmoid(x)
// ---------------------------------------------------------------------------
__device__ __forceinline__ void gate_av(float z, float hi, float& a, float& v)
{
    const float e  = __expf(-z);
    const float sz = 1.0f / (1.0f + e);        // sigmoid(z)
    a = e * sz;                                // sigmoid(-z)
    const float g = (hi >= 0.0f) ? (hi + 0.5f)
                                 : (1.0f / (1.0f + __expf(-hi)));
    v = sz * g;
}

// Phase 1: per-(channel-pair, chunk) affine summary  h_out = A*h_in + B.
__global__ __launch_bounds__(256) void scan_phase1(
    const __half* __restrict__ zbuf, const __half* __restrict__ hbuf,
    float* __restrict__ Aar, float* __restrict__ Bar)
{
    const int idx = blockIdx.x * 256 + threadIdx.x;   // 0..262143
    const int h2  = (idx & 511) << 1;
    const int n   = (idx >> 9) & 7;
    const int c   = idx >> 12;                        // 0..63
    const size_t base = ((size_t)(n * L_SEQ + c * CLEN)) * H_DIM + h2;
    const __half2* zp = (const __half2*)(zbuf + base);
    const __half2* hp = (const __half2*)(hbuf + base);

    float A0 = 1.f, B0 = 0.f, A1 = 1.f, B1 = 0.f;
#pragma unroll 8
    for (int s = 0; s < CLEN; ++s) {
        const float2 z  = __half22float2(zp[(size_t)s * (H_DIM / 2)]);
        const float2 hi = __half22float2(hp[(size_t)s * (H_DIM / 2)]);
        float a, v;
        gate_av(z.x, hi.x, a, v);  B0 = fmaf(a, B0, v);  A0 *= a;
        gate_av(z.y, hi.y, a, v);  B1 = fmaf(a, B1, v);  A1 *= a;
    }
    *(float2*)(Aar + 2 * (size_t)idx) = make_float2(A0, A1);
    *(float2*)(Bar + 2 * (size_t)idx) = make_float2(B0, B1);
}

// Phase 2: compose NCHUNK chunk summaries per channel, seeded with hx (fp32).
__global__ __launch_bounds__(256) void scan_phase2(
    const float* __restrict__ Aar, const float* __restrict__ Bar,
    const float* __restrict__ hx, float* __restrict__ seed)
{
    const int ch = blockIdx.x * 256 + threadIdx.x;    // 0..8191
    float carry = hx[ch];
#pragma unroll
    for (int c = 0; c < NCHUNK; ++c) {
        seed[c * NCH + ch] = carry;
        carry = fmaf(Aar[c * NCH + ch], carry, Bar[c * NCH + ch]);
    }
}

// Phase 3: replay each chunk from its seed, write fp32 output.
__global__ __launch_bounds__(256) void scan_phase3(
    const __half* __restrict__ zbuf, const __half* __restrict__ hbuf,
    const float* __restrict__ seed, float* __restrict__ out)
{
    const int idx = blockIdx.x * 256 + threadIdx.x;
    const int h2  = (idx & 511) << 1;
    const int n   = (idx >> 9) & 7;
    const int c   = idx >> 12;
    const size_t base = ((size_t)(n * L_SEQ + c * CLEN)) * H_DIM + h2;
    const __half2* zp = (const __half2*)(zbuf + base);
    const __half2* hp = (const __half2*)(hbuf + base);
    float* op = out + base;

    float2 hcur = *(const float2*)(seed + 2 * (size_t)idx);
#pragma unroll 4
    for (int s = 0; s < CLEN; ++s) {
        const float2 z  = __half22float2(zp[(size_t)s * (H_DIM / 2)]);
        const float2 hi = __half22float2(hp[(size_t)s * (H_DIM / 2)]);
        float a, v;
        gate_av(z.x, hi.x, a, v);  hcur.x = fmaf(a, hcur.x, v);
        gate_av(z.y, hi.y, a, v);  hcur.y = fmaf(a, hcur.y, v);
        *(float2*)(op + (size_t)s * H_DIM) = hcur;
    }
}

// ---------------------------------------------------------------------------
extern "C" void kernel_launch(void* const* d_in, const int* in_sizes, int n_in,
                              void* d_out, int out_size, void* d_ws, size_t ws_size,
                              hipStream_t stream)
{
    const float* X    = (const float*)d_in[0];   // x  (8,4096,1024) fp32
    const float* Wm   = (const float*)d_in[1];   // W  (2048,1024)   fp32
    const float* bias = (const float*)d_in[2];   // b  (2048)        fp32
    const float* hx   = (const float*)d_in[3];   // hx (8,1024)      fp32
    float* out = (float*)d_out;                  // (8,4096,1024)    fp32

    char* ws = (char*)d_ws;
    ushort_t* wb = (ushort_t*)ws;                                  //  4 MB
    __half* zbuf = (__half*)(ws + (size_t)O_DIM * K_DIM * 2);      // 67 MB
    __half* hbuf = zbuf + (size_t)M_TOT * H_DIM;                   // 67 MB
    float*  Aar  = (float*)(hbuf + (size_t)M_TOT * H_DIM);
    float*  Bar  = Aar + (size_t)NCHUNK * NCH;
    float*  seed = Bar + (size_t)NCHUNK * NCH;

    // x_bf16 lives in the first half of d_out (scratch until phase3 rewrites)
    ushort_t* xb = (ushort_t*)d_out;

    cvt_f32_bf16<<<O_DIM * K_DIM / 8 / 256, 256, 0, stream>>>(Wm, wb);
    cvt_f32_bf16<<<M_TOT * K_DIM / 8 / 256, 256, 0, stream>>>(X, xb);

    dim3 ggrid(O_DIM / BN, M_TOT / BM);          // (16, 256): O fast for reuse
    gemm_zh<<<ggrid, 256, 0, stream>>>(xb, wb, bias, zbuf, hbuf);

    const int p13_blocks = (NCH / 2) * NCHUNK / 256;   // 1024
    scan_phase1<<<p13_blocks, 256, 0, stream>>>(zbuf, hbuf, Aar, Bar);
    scan_phase2<<<NCH / 256, 256, 0, stream>>>(Aar, Bar, hx, seed);
    scan_phase3<<<p13_blocks, 256, 0, stream>>>(zbuf, hbuf, seed, out);
}

// Round 5
// 476.877 us; speedup vs baseline: 1.4584x; 1.0474x over previous
//
#include <hip/hip_runtime.h>
#include <hip/hip_bf16.h>
#include <hip/hip_fp16.h>

// ============================================================================
// MinGRUCell forward, MI355X (gfx950).  Round 5 = round 4 + OOB fix.
//   zh = x @ W^T + b     (x,W rounded to bf16, MFMA GEMM, global_load_lds)
//   h[t] = sigmoid(-z)*h[t-1] + sigmoid(z)*g(h_inter), h[-1]=hx  (linear scan)
//
// Round-4 aborted: Aar was placed at out + M_TOT*H_DIM -- the END of d_out
// (output is exactly M_TOT*H_DIM floats), so phase1 wrote 8 MiB OOB. xb
// (bf16) occupies exactly the first HALF of d_out; Aar belongs at
// out + M_TOT*H_DIM/2. One-line fix; scan rewrite itself audits clean.
//
// Workspace: wb bf16 4MiB | zbuf fp16 64MiB | hbuf fp16 64MiB | seed 4MiB
// d_out scratch (until phase3 overwrites): xb [0,64MiB) | Aar,Bar [64,72MiB)
// ============================================================================

#define N_B   8
#define L_SEQ 4096
#define H_DIM 1024
#define K_DIM 1024
#define O_DIM 2048
#define M_TOT (N_B * L_SEQ)      // 32768 GEMM rows

#define BM 128
#define BN 128
#define BK 64

#define NCHUNK 128
#define CLEN   (L_SEQ / NCHUNK)  // 32
#define NCH    (N_B * H_DIM)     // 8192 channels

typedef unsigned short ushort_t;
typedef unsigned short us8 __attribute__((ext_vector_type(8)));
typedef __bf16 v8bf __attribute__((ext_vector_type(8)));
typedef float f32x4 __attribute__((ext_vector_type(4)));

static __device__ __forceinline__ ushort_t f2bf(float f) {
    __hip_bfloat16 h = __float2bfloat16(f);   // RTN
    return *reinterpret_cast<ushort_t*>(&h);
}

// async global->LDS DMA, 16B per lane, LDS dest = wave-uniform base + lane*16
static __device__ __forceinline__ void dma16(const ushort_t* g, ushort_t* l) {
    __builtin_amdgcn_global_load_lds(
        (const __attribute__((address_space(1))) unsigned int*)g,
        (__attribute__((address_space(3))) unsigned int*)l,
        16, 0, 0);
}

// ---------------------------------------------------------------------------
// fp32 -> bf16 (8 elems/thread)
// ---------------------------------------------------------------------------
__global__ __launch_bounds__(256) void cvt_f32_bf16(
    const float* __restrict__ src, ushort_t* __restrict__ dst)
{
    const int i = blockIdx.x * 256 + threadIdx.x;
    const float4 f0 = ((const float4*)src)[2 * i];
    const float4 f1 = ((const float4*)src)[2 * i + 1];
    us8 o;
    o[0] = f2bf(f0.x); o[1] = f2bf(f0.y); o[2] = f2bf(f0.z); o[3] = f2bf(f0.w);
    o[4] = f2bf(f1.x); o[5] = f2bf(f1.y); o[6] = f2bf(f1.z); o[7] = f2bf(f1.w);
    ((us8*)dst)[i] = o;
}

// ---------------------------------------------------------------------------
// GEMM (unchanged from round 3: m97-plateau, 859 TF).
// C[m,o] = sum_k xb[m,k]*Wb[o,k] + b[o]; 128x128 tile, 4 waves,
// mfma_f32_16x16x32_bf16, global_load_lds dwordx4 staging, XOR swizzle on the
// global source address side (DMA dest is wave-uniform base + lane*16).
// ---------------------------------------------------------------------------
__global__ __launch_bounds__(256) void gemm_zh(
    const ushort_t* __restrict__ Xb,       // (M_TOT, K) bf16 bits
    const ushort_t* __restrict__ Wb,       // (O_DIM, K) bf16 bits
    const float* __restrict__ bias,        // (O_DIM) fp32
    __half* __restrict__ zbuf,             // (M_TOT, H_DIM) fp16
    __half* __restrict__ hbuf)             // (M_TOT, H_DIM) fp16
{
    __shared__ ushort_t As[BM * BK];
    __shared__ ushort_t Bs[BN * BK];

    const int tid    = threadIdx.x;
    const int wave   = tid >> 6;
    const int lane   = tid & 63;
    const int lane15 = lane & 15;
    const int quad   = lane >> 4;

    const int n0 = blockIdx.x * BN;        // O-tile fast -> A-tile L2 reuse
    const int m0 = blockIdx.y * BM;

    const int lrow = lane >> 3;            // 0..7
    const int jj   = (lane & 7) ^ lrow;    // global chunk (xor swizzle)
    const ushort_t* gA = Xb + (size_t)(m0 + wave * 8 + lrow) * K_DIM + jj * 8;
    const ushort_t* gB = Wb + (size_t)(n0 + wave * 8 + lrow) * K_DIM + jj * 8;
    ushort_t* lA = &As[(wave * 8) * BK];
    ushort_t* lB = &Bs[(wave * 8) * BK];

    const int wm = (wave >> 1) * 64;
    const int wn = (wave & 1) * 64;

    int offA[2][4], offB[2][4];
#pragma unroll
    for (int s = 0; s < 2; ++s) {
#pragma unroll
        for (int t = 0; t < 4; ++t) {
            const int rowA = wm + t * 16 + lane15;
            offA[s][t] = rowA * BK + (((s * 4 + quad) ^ (rowA & 7)) * 8);
            const int rowB = wn + t * 16 + lane15;
            offB[s][t] = rowB * BK + (((s * 4 + quad) ^ (rowB & 7)) * 8);
        }
    }

    const f32x4 fzero = {0.f, 0.f, 0.f, 0.f};
    f32x4 acc[4][4];
#pragma unroll
    for (int i = 0; i < 4; ++i)
#pragma unroll
        for (int j = 0; j < 4; ++j)
            acc[i][j] = fzero;

    for (int kt = 0; kt < K_DIM / BK; ++kt) {
        __syncthreads();
#pragma unroll
        for (int r = 0; r < 4; ++r) {
            dma16(gA + (size_t)r * 32 * K_DIM + kt * BK, lA + r * 32 * BK);
            dma16(gB + (size_t)r * 32 * K_DIM + kt * BK, lB + r * 32 * BK);
        }
        __syncthreads();

#pragma unroll
        for (int s = 0; s < 2; ++s) {
            v8bf af[4], bfr[4];
#pragma unroll
            for (int t = 0; t < 4; ++t) af[t]  = *(const v8bf*)(&As[offA[s][t]]);
#pragma unroll
            for (int t = 0; t < 4; ++t) bfr[t] = *(const v8bf*)(&Bs[offB[s][t]]);
#pragma unroll
            for (int i = 0; i < 4; ++i)
#pragma unroll
                for (int j = 0; j < 4; ++j)
                    acc[i][j] = __builtin_amdgcn_mfma_f32_16x16x32_bf16(
                        af[i], bfr[j], acc[i][j], 0, 0, 0);
        }
    }

    float bv[4];
#pragma unroll
    for (int j = 0; j < 4; ++j)
        bv[j] = bias[n0 + wn + j * 16 + lane15];

    __half* outb = (n0 < H_DIM) ? zbuf : hbuf;      // block-uniform
    const int colbase = (n0 & (H_DIM - 1)) + wn + lane15;

#pragma unroll
    for (int i = 0; i < 4; ++i) {
#pragma unroll
        for (int r = 0; r < 4; ++r) {
            const size_t row = (size_t)(m0 + wm + i * 16 + quad * 4 + r);
            __half* p = outb + row * H_DIM + colbase;
#pragma unroll
            for (int j = 0; j < 4; ++j)
                p[j * 16] = __float2half(acc[i][j][r] + bv[j]);
        }
    }
}

// ---------------------------------------------------------------------------
// Gating math (identical in phases 1 and 3).
// a = sigmoid(-z), v = sigmoid(z)*g(hi);  g(x) = x+0.5 (x>=0) else sigmoid(x)
// ---------------------------------------------------------------------------
__device__ __forceinline__ void gate_av(float z, float hi, float& a, float& v)
{
    const float e  = __expf(-z);
    const float sz = 1.0f / (1.0f + e);        // sigmoid(z)
    a = e * sz;                                // sigmoid(-z)
    const float g = (hi >= 0.0f) ? (hi + 0.5f)
                                 : (1.0f / (1.0f + __expf(-hi)));
    v = sz * g;
}

// Phase 1: per-(8-channel group, chunk) affine summary  h_out = A*h_in + B.
// 16B loads per buffer per step (G13).
__global__ __launch_bounds__(256) void scan_phase1(
    const __half* __restrict__ zbuf, const __half* __restrict__ hbuf,
    float* __restrict__ Aar, float* __restrict__ Bar)
{
    const int idx = blockIdx.x * 256 + threadIdx.x;   // 0..131071
    const int h8  = (idx & 127) << 3;
    const int n   = (idx >> 7) & 7;
    const int c   = idx >> 10;                        // 0..127
    const size_t base = ((size_t)(n * L_SEQ + c * CLEN)) * H_DIM + h8;
    const float4* zp = (const float4*)(zbuf + base);  // float4 == 8 halves
    const float4* hp = (const float4*)(hbuf + base);

    float A[8], B[8];
#pragma unroll
    for (int j = 0; j < 8; ++j) { A[j] = 1.f; B[j] = 0.f; }

#pragma unroll 4
    for (int s = 0; s < CLEN; ++s) {
        float4 zr = zp[(size_t)s * (H_DIM / 8)];
        float4 hr = hp[(size_t)s * (H_DIM / 8)];
        const __half2* z2 = (const __half2*)&zr;
        const __half2* i2 = (const __half2*)&hr;
#pragma unroll
        for (int j = 0; j < 4; ++j) {
            const float2 z  = __half22float2(z2[j]);
            const float2 hi = __half22float2(i2[j]);
            float a, v;
            gate_av(z.x, hi.x, a, v);
            B[2*j]   = fmaf(a, B[2*j],   v);  A[2*j]   *= a;
            gate_av(z.y, hi.y, a, v);
            B[2*j+1] = fmaf(a, B[2*j+1], v);  A[2*j+1] *= a;
        }
    }
    const size_t o = (size_t)c * NCH + n * H_DIM + h8;
    *(float4*)(Aar + o)     = *(const float4*)&A[0];
    *(float4*)(Aar + o + 4) = *(const float4*)&A[4];
    *(float4*)(Bar + o)     = *(const float4*)&B[0];
    *(float4*)(Bar + o + 4) = *(const float4*)&B[4];
}

// Phase 2: compose NCHUNK chunk summaries per channel, seeded with hx (fp32).
__global__ __launch_bounds__(256) void scan_phase2(
    const float* __restrict__ Aar, const float* __restrict__ Bar,
    const float* __restrict__ hx, float* __restrict__ seed)
{
    const int ch = blockIdx.x * 256 + threadIdx.x;    // 0..8191
    float carry = hx[ch];
#pragma unroll 8
    for (int c = 0; c < NCHUNK; ++c) {
        seed[c * NCH + ch] = carry;
        carry = fmaf(Aar[c * NCH + ch], carry, Bar[c * NCH + ch]);
    }
}

// Phase 3: replay each chunk from its seed; 16B loads, 2x16B stores per step.
__global__ __launch_bounds__(256) void scan_phase3(
    const __half* __restrict__ zbuf, const __half* __restrict__ hbuf,
    const float* __restrict__ seed, float* __restrict__ out)
{
    const int idx = blockIdx.x * 256 + threadIdx.x;
    const int h8  = (idx & 127) << 3;
    const int n   = (idx >> 7) & 7;
    const int c   = idx >> 10;
    const size_t base = ((size_t)(n * L_SEQ + c * CLEN)) * H_DIM + h8;
    const float4* zp = (const float4*)(zbuf + base);
    const float4* hp = (const float4*)(hbuf + base);
    float* op = out + base;

    const size_t so = (size_t)c * NCH + n * H_DIM + h8;
    float h0[4], h1[4];
    *(float4*)h0 = *(const float4*)(seed + so);
    *(float4*)h1 = *(const float4*)(seed + so + 4);

#pragma unroll 4
    for (int s = 0; s < CLEN; ++s) {
        float4 zr = zp[(size_t)s * (H_DIM / 8)];
        float4 hr = hp[(size_t)s * (H_DIM / 8)];
        const __half2* z2 = (const __half2*)&zr;
        const __half2* i2 = (const __half2*)&hr;
#pragma unroll
        for (int j = 0; j < 2; ++j) {
            const float2 za = __half22float2(z2[j]);
            const float2 ia = __half22float2(i2[j]);
            float a, v;
            gate_av(za.x, ia.x, a, v);  h0[2*j]   = fmaf(a, h0[2*j],   v);
            gate_av(za.y, ia.y, a, v);  h0[2*j+1] = fmaf(a, h0[2*j+1], v);
            const float2 zb = __half22float2(z2[2+j]);
            const float2 ib = __half22float2(i2[2+j]);
            gate_av(zb.x, ib.x, a, v);  h1[2*j]   = fmaf(a, h1[2*j],   v);
            gate_av(zb.y, ib.y, a, v);  h1[2*j+1] = fmaf(a, h1[2*j+1], v);
        }
        float* pr = op + (size_t)s * H_DIM;
        *(float4*)pr       = *(const float4*)h0;
        *(float4*)(pr + 4) = *(const float4*)h1;
    }
}

// ---------------------------------------------------------------------------
extern "C" void kernel_launch(void* const* d_in, const int* in_sizes, int n_in,
                              void* d_out, int out_size, void* d_ws, size_t ws_size,
                              hipStream_t stream)
{
    const float* X    = (const float*)d_in[0];   // x  (8,4096,1024) fp32
    const float* Wm   = (const float*)d_in[1];   // W  (2048,1024)   fp32
    const float* bias = (const float*)d_in[2];   // b  (2048)        fp32
    const float* hx   = (const float*)d_in[3];   // hx (8,1024)      fp32
    float* out = (float*)d_out;                  // (8,4096,1024)    fp32

    char* ws = (char*)d_ws;
    ushort_t* wb = (ushort_t*)ws;                                  //  4 MiB
    __half* zbuf = (__half*)(ws + (size_t)O_DIM * K_DIM * 2);      // 64 MiB
    __half* hbuf = zbuf + (size_t)M_TOT * H_DIM;                   // 64 MiB
    float*  seed = (float*)(hbuf + (size_t)M_TOT * H_DIM);         //  4 MiB

    // d_out (128 MiB) doubles as scratch until phase3 overwrites it:
    //   bytes [0, 64Mi):   x_bf16  (M_TOT*K_DIM*2 B = exactly half)
    //   bytes [64Mi,72Mi): Aar, Bar (NCHUNK*NCH fp32 each)
    ushort_t* xb = (ushort_t*)d_out;
    float* Aar = out + (size_t)M_TOT * H_DIM / 2;      // FIXED: true halfway
    float* Bar = Aar + (size_t)NCHUNK * NCH;

    cvt_f32_bf16<<<O_DIM * K_DIM / 8 / 256, 256, 0, stream>>>(Wm, wb);
    cvt_f32_bf16<<<M_TOT * K_DIM / 8 / 256, 256, 0, stream>>>(X, xb);

    dim3 ggrid(O_DIM / BN, M_TOT / BM);          // (16, 256): O fast for reuse
    gemm_zh<<<ggrid, 256, 0, stream>>>(xb, wb, bias, zbuf, hbuf);

    const int p13_blocks = (NCH / 8) * NCHUNK / 256;   // 512
    scan_phase1<<<p13_blocks, 256, 0, stream>>>(zbuf, hbuf, Aar, Bar);
    scan_phase2<<<NCH / 256, 256, 0, stream>>>(Aar, Bar, hx, seed);
    scan_phase3<<<p13_blocks, 256, 0, stream>>>(zbuf, hbuf, seed, out);
}